// Round 1
// baseline (5331.590 us; speedup 1.0000x reference)
//
#include <hip/hip_runtime.h>

#define C_IN 256
#define PLANE 4096          // 64*64
#define KW 2304             // C_IN*9
#define OFF_ELEMS 294912    // 4*18*64*64
#define CLS_OFF   589824    // 2*OFF_ELEMS

// ---------------------------------------------------------------------------
// conv3x3 (pad 1, no bias) as implicit GEMM.  DEFORM=true samples the input
// bilinearly at precomputed positions (torchvision DeformConv2d v1 semantics).
// Block: 64 co x 64 px (one output row y).  256 threads, 4x4 register tile.
// ---------------------------------------------------------------------------
template <bool DEFORM>
__global__ __launch_bounds__(256) void conv_gemm_t(
    const float* __restrict__ in, const float* __restrict__ w,
    float* __restrict__ out, int Cout,
    const int4* __restrict__ idx4, const float4* __restrict__ wt4) {
  __shared__ __align__(16) float As[32][64];   // [k][px]
  __shared__ __align__(16) float WsT[32][68];  // [k][co] padded
  const int y   = blockIdx.x;        // output row 0..63
  const int cob = blockIdx.y * 64;   // co tile base
  const int b   = blockIdx.z;
  const int t   = threadIdx.x;
  const int tpx = (t & 15) * 4;      // pixel base within row
  const int tco = (t >> 4) * 4;      // co base within tile

  float acc[4][4] = {};
  const float* inb = in + (size_t)b * (C_IN * PLANE);

  for (int kc = 0; kc < KW; kc += 32) {
    // ---- stage A (im2col or deform-sampled), 32 x 64 ----
#pragma unroll
    for (int l0 = 0; l0 < 2048; l0 += 256) {
      int l = l0 + t;
      int kl = l >> 6, px = l & 63;
      int kidx = kc + kl;
      int ci = kidx / 9, kk = kidx % 9;
      float v;
      if (!DEFORM) {
        int ky = kk / 3, kx = kk % 3;
        int iy = y + ky - 1, ix = px + kx - 1;
        v = 0.f;
        if ((unsigned)iy < 64u && (unsigned)ix < 64u)
          v = inb[ci * PLANE + iy * 64 + ix];
      } else {
        int pi = ((b * 9 + kk) * 64 + y) * 64 + px;
        int4  id = idx4[pi];
        float4 wt = wt4[pi];
        const float* plane = inb + ci * PLANE;
        v = wt.x * plane[id.x] + wt.y * plane[id.y] +
            wt.z * plane[id.z] + wt.w * plane[id.w];
      }
      As[kl][px] = v;
    }
    // ---- stage W transposed, 32 x 64 ----
#pragma unroll
    for (int l0 = 0; l0 < 2048; l0 += 256) {
      int l = l0 + t;
      int col = l >> 5, kl = l & 31;
      int co = cob + col;
      WsT[kl][col] = (co < Cout) ? w[co * KW + kc + kl] : 0.f;
    }
    __syncthreads();
    // ---- compute ----
#pragma unroll
    for (int k = 0; k < 32; ++k) {
      const float4 a  = *reinterpret_cast<const float4*>(&As[k][tpx]);
      const float4 wv = *reinterpret_cast<const float4*>(&WsT[k][tco]);
#pragma unroll
      for (int j = 0; j < 1; ++j) {}  // (keep compiler happy about unroll scope)
      acc[0][0] += wv.x * a.x; acc[0][1] += wv.x * a.y; acc[0][2] += wv.x * a.z; acc[0][3] += wv.x * a.w;
      acc[1][0] += wv.y * a.x; acc[1][1] += wv.y * a.y; acc[1][2] += wv.y * a.z; acc[1][3] += wv.y * a.w;
      acc[2][0] += wv.z * a.x; acc[2][1] += wv.z * a.y; acc[2][2] += wv.z * a.z; acc[2][3] += wv.z * a.w;
      acc[3][0] += wv.w * a.x; acc[3][1] += wv.w * a.y; acc[3][2] += wv.w * a.z; acc[3][3] += wv.w * a.w;
    }
    __syncthreads();
  }
#pragma unroll
  for (int i = 0; i < 4; ++i) {
    int co = cob + tco + i;
    if (co < Cout) {
      float4 v = make_float4(acc[i][0], acc[i][1], acc[i][2], acc[i][3]);
      *reinterpret_cast<float4*>(
          &out[(((size_t)b * Cout + co) * 64 + y) * 64 + tpx]) = v;
    }
  }
}

// ---------------------------------------------------------------------------
// Precompute bilinear taps for deform conv: per (b,k,y,x) 4 clipped in-plane
// offsets + 4 masked weights.
// ---------------------------------------------------------------------------
__global__ __launch_bounds__(256) void precomp_offsets(
    const float* __restrict__ off, int4* __restrict__ idx4,
    float4* __restrict__ wt4) {
  int tid = blockIdx.x * 256 + threadIdx.x;
  if (tid >= 4 * 9 * PLANE) return;
  int x = tid & 63;
  int y = (tid >> 6) & 63;
  int kk = (tid >> 12) % 9;
  int b = tid / (9 * PLANE);
  float dy = off[((b * 18 + 2 * kk) * 64 + y) * 64 + x];
  float dx = off[((b * 18 + 2 * kk + 1) * 64 + y) * 64 + x];
  float sy = dy + (float)(y - 1 + kk / 3);
  float sx = dx + (float)(x - 1 + kk % 3);
  float y0f = floorf(sy), x0f = floorf(sx);
  float wy = sy - y0f, wx = sx - x0f;
  int y0 = (int)y0f, x0 = (int)x0f;
  int y1 = y0 + 1, x1 = x0 + 1;
  float vy0 = ((unsigned)y0 < 64u) ? 1.f : 0.f;
  float vy1 = ((unsigned)y1 < 64u) ? 1.f : 0.f;
  float vx0 = ((unsigned)x0 < 64u) ? 1.f : 0.f;
  float vx1 = ((unsigned)x1 < 64u) ? 1.f : 0.f;
  int cy0 = min(max(y0, 0), 63), cy1 = min(max(y1, 0), 63);
  int cx0 = min(max(x0, 0), 63), cx1 = min(max(x1, 0), 63);
  idx4[tid] = make_int4(cy0 * 64 + cx0, cy0 * 64 + cx1,
                        cy1 * 64 + cx0, cy1 * 64 + cx1);
  wt4[tid] = make_float4((1.f - wy) * (1.f - wx) * vy0 * vx0,
                         (1.f - wy) * wx * vy0 * vx1,
                         wy * (1.f - wx) * vy1 * vx0,
                         wy * wx * vy1 * vx1);
}

// ---------------------------------------------------------------------------
// GroupNorm: stats (mean, rsqrt(var+eps)) per (b, group of 8 channels)
// ---------------------------------------------------------------------------
__global__ __launch_bounds__(256) void gn_stats(const float* __restrict__ x,
                                                float2* __restrict__ stats) {
  int bg = blockIdx.x;  // b*32+g ; group = 8 contiguous channels
  const float4* p = reinterpret_cast<const float4*>(x + (size_t)bg * 32768);
  float s = 0.f, q = 0.f;
  for (int i = threadIdx.x; i < 8192; i += 256) {
    float4 v = p[i];
    s += v.x + v.y + v.z + v.w;
    q += v.x * v.x + v.y * v.y + v.z * v.z + v.w * v.w;
  }
#pragma unroll
  for (int o = 32; o; o >>= 1) {
    s += __shfl_xor(s, o);
    q += __shfl_xor(q, o);
  }
  __shared__ float ss[4], qq[4];
  int wid = threadIdx.x >> 6;
  if ((threadIdx.x & 63) == 0) { ss[wid] = s; qq[wid] = q; }
  __syncthreads();
  if (threadIdx.x == 0) {
    s = ss[0] + ss[1] + ss[2] + ss[3];
    q = qq[0] + qq[1] + qq[2] + qq[3];
    float m = s / 32768.f;
    float v = q / 32768.f - m * m;
    stats[bg] = make_float2(m, rsqrtf(v + 1e-5f));
  }
}

__global__ __launch_bounds__(256) void gn_apply(
    const float* __restrict__ x, const float2* __restrict__ stats,
    const float* __restrict__ gamma, const float* __restrict__ beta,
    float* __restrict__ out) {
  int i = blockIdx.x * 256 + threadIdx.x;  // over float4, 1048576 total
  float4 v = reinterpret_cast<const float4*>(x)[i];
  int e = i >> 10;          // b*256 + c
  int c = e & 255;
  float2 st = stats[e >> 3];  // b*32 + c/8
  float a = st.y * gamma[c];
  float bb = beta[c] - st.x * a;
  v.x = v.x * a + bb; v.y = v.y * a + bb;
  v.z = v.z * a + bb; v.w = v.w * a + bb;
  reinterpret_cast<float4*>(out)[i] = v;
}

// ---------------------------------------------------------------------------
// rep points: rp1 = grid_init + off1 ; rp2 = rp1 + off2
// ---------------------------------------------------------------------------
__global__ __launch_bounds__(256) void rp_out(const float* __restrict__ off1,
                                              const float* __restrict__ off2,
                                              float* __restrict__ out) {
  int tid = blockIdx.x * 256 + threadIdx.x;  // 294912
  if (tid >= OFF_ELEMS) return;
  int x = tid & 63, y = (tid >> 6) & 63;
  int ch = (tid >> 12) % 18;
  int k = ch >> 1;
  float base = (ch & 1) ? (float)(x + (k % 3) - 1) : (float)(y + (k / 3) - 1);
  float r1 = base + off1[tid];
  out[tid] = r1;
  out[OFF_ELEMS + tid] = r1 + off2[tid];
}

// ---------------------------------------------------------------------------
extern "C" void kernel_launch(void* const* d_in, const int* in_sizes, int n_in,
                              void* d_out, int out_size, void* d_ws,
                              size_t ws_size, hipStream_t stream) {
  (void)in_sizes; (void)n_in; (void)out_size; (void)ws_size;
  const float* feature = (const float*)d_in[0];
  const float* loc_ws  = (const float*)d_in[1];
  const float* loc_g   = (const float*)d_in[2];
  const float* loc_b   = (const float*)d_in[3];
  const float* cls_ws  = (const float*)d_in[4];
  const float* cls_g   = (const float*)d_in[5];
  const float* cls_b   = (const float*)d_in[6];
  const float* pi_w    = (const float*)d_in[7];
  const float* pio_w   = (const float*)d_in[8];
  const float* prd_w   = (const float*)d_in[9];
  const float* pro_w   = (const float*)d_in[10];
  const float* cd_w    = (const float*)d_in[11];
  const float* co_w    = (const float*)d_in[12];
  float* out = (float*)d_out;

  float*  bufA  = (float*)d_ws;                    // 4*256*4096
  float*  bufB  = bufA + 4194304;                  // 4*256*4096
  float*  off1  = bufB + 4194304;                  // 294912
  float*  off2  = off1 + OFF_ELEMS;                // 294912
  int4*   idx4  = (int4*)(off2 + OFF_ELEMS);       // 147456 int4
  float4* wt4   = (float4*)(idx4 + 147456);        // 147456 float4
  float2* stats = (float2*)(wt4 + 147456);         // 128 float2

  dim3 blk(256);
  auto conv = [&](const float* in, const float* w, float* o, int Cout) {
    dim3 g(64, (Cout + 63) / 64, 4);
    conv_gemm_t<false><<<g, blk, 0, stream>>>(in, w, o, Cout, nullptr, nullptr);
  };
  auto dconv = [&](const float* in, const float* w, float* o) {
    dim3 g(64, 4, 4);
    conv_gemm_t<true><<<g, blk, 0, stream>>>(in, w, o, 256, idx4, wt4);
  };
  auto gn = [&](const float* in, const float* g, const float* b, float* o) {
    gn_stats<<<dim3(128), blk, 0, stream>>>(in, stats);
    gn_apply<<<dim3(4096), blk, 0, stream>>>(in, stats, g, b, o);
  };

  // ---- loc branch ----
  conv(feature, loc_ws + 0 * 589824, bufA, 256);
  gn(bufA, loc_g + 0,   loc_b + 0,   bufB);
  conv(bufB, loc_ws + 1 * 589824, bufA, 256);
  gn(bufA, loc_g + 256, loc_b + 256, bufB);
  conv(bufB, loc_ws + 2 * 589824, bufA, 256);
  gn(bufA, loc_g + 512, loc_b + 512, bufB);        // bufB = loc
  conv(bufB, pi_w, bufA, 256);
  conv(bufA, pio_w, off1, 18);                     // offset1
  precomp_offsets<<<dim3(576), blk, 0, stream>>>(off1, idx4, wt4);
  dconv(bufB, prd_w, bufA);                        // deform(loc, offset1)
  conv(bufA, pro_w, off2, 18);                     // offset2

  // ---- cls branch ----
  conv(feature, cls_ws + 0 * 589824, bufA, 256);
  gn(bufA, cls_g + 0,   cls_b + 0,   bufB);
  conv(bufB, cls_ws + 1 * 589824, bufA, 256);
  gn(bufA, cls_g + 256, cls_b + 256, bufB);
  conv(bufB, cls_ws + 2 * 589824, bufA, 256);
  gn(bufA, cls_g + 512, cls_b + 512, bufB);        // bufB = clsf
  dconv(bufB, cd_w, bufA);                         // deform(clsf, offset1)
  conv(bufA, co_w, out + CLS_OFF, 15);             // classification

  // ---- rep points ----
  rp_out<<<dim3(1152), blk, 0, stream>>>(off1, off2, out);
}

// Round 3
// 2663.663 us; speedup vs baseline: 2.0016x; 2.0016x over previous
//
#include <hip/hip_runtime.h>

#define PLANE 4096
#define OFF_ELEMS 294912
#define CLS_OFF   589824

typedef __attribute__((ext_vector_type(4))) float f32x4;
typedef __attribute__((ext_vector_type(8))) short bf16x8;

__device__ __forceinline__ float bf2f(ushort u) {
  union { uint u; float f; } x; x.u = ((uint)u) << 16; return x.f;
}
__device__ __forceinline__ ushort f2bf(float f) {
  union { float f; uint u; } x; x.f = f;
  return (ushort)((x.u + 0x7fffu + ((x.u >> 16) & 1u)) >> 16);
}

// ---------------------------------------------------------------------------
// bf16 MFMA conv3x3 (pad 1).  GEMM: D[co][px] = sum_k W[co][k] * Im[k][px].
// Tile: CO_TILE co x 64 px (one output row).  K-loop: 9 taps x 4 ci-chunks of 64.
// A-frags (W) loaded directly from global (tap-major bf16 layout [9][Cout][256]).
// B-frags (im2col) from LDS stored transposed [px][k] (pad 88 -> 2-way banks).
// ---------------------------------------------------------------------------
template <int CO_TILE, bool DEFORM, bool OUT_BF16>
__global__ __launch_bounds__(256) void conv_mfma(
    const ushort* __restrict__ inb, const ushort* __restrict__ wg,
    void* __restrict__ outp, int Cout,
    const int4* __restrict__ idx4, const float4* __restrict__ wt4) {
  constexpr int WM_WAVES = (CO_TILE == 128) ? 2 : 1;
  constexpr int WM_SUB = CO_TILE / WM_WAVES;   // 64 or 32
  constexpr int MFR = WM_SUB / 16;             // 4 or 2
  constexpr int WN_WAVES = 4 / WM_WAVES;       // 2 or 4
  constexpr int PX_SUB = 64 / WN_WAVES;        // 32 or 16
  constexpr int NFR = PX_SUB / 16;             // 2 or 1

  __shared__ __align__(16) ushort As[64][88];  // [px][k], pad 88 (2-way banks)

  const int y = blockIdx.x;
  const int cob = blockIdx.y * CO_TILE;
  const int b = blockIdx.z;
  const int t = threadIdx.x;
  const int wv = t >> 6, lane = t & 63, lm = lane & 15, kg = lane >> 4;
  const int wm = (WM_WAVES == 2) ? (wv & 1) : 0;
  const int wn = (WM_WAVES == 2) ? (wv >> 1) : wv;

  f32x4 acc[MFR][NFR] = {};
  const ushort* inb_b = inb + (size_t)b * 256 * PLANE;

  for (int kk = 0; kk < 9; ++kk) {
    const int ky = kk / 3, kx = kk % 3;
    const int iy = y + ky - 1;
    if (!DEFORM && (iy < 0 || iy >= 64)) continue;

    int4 did[4]; float4 dwt[4];
    if (DEFORM) {
      int base = ((b * 9 + kk) * 64 + y) * 64 + (t >> 4) * 4;
#pragma unroll
      for (int p = 0; p < 4; ++p) { did[p] = idx4[base + p]; dwt[p] = wt4[base + p]; }
    }

    for (int cc = 0; cc < 4; ++cc) {
      const int cib = cc * 64;
      // ---------------- stage im2col tile (transposed) ----------------
      if (!DEFORM) {
        const int ci2 = t & 31, x0 = (t >> 5) * 8;
        const ushort* r0 = inb_b + ((size_t)(cib + 2 * ci2) * 64 + iy) * 64 + x0;
        uint4 va = *(const uint4*)r0;
        uint4 vb = *(const uint4*)(r0 + PLANE);
        const ushort* ap = (const ushort*)&va;
        const ushort* bp = (const ushort*)&vb;
#pragma unroll
        for (int j = 0; j < 8; ++j) {
          int px = x0 + j + 1 - kx;
          if (px >= 0 && px < 64)
            *(uint*)&As[px][2 * ci2] = (uint)ap[j] | ((uint)bp[j] << 16);
        }
        if (kx == 0 && x0 == 0)  *(uint*)&As[0][2 * ci2] = 0u;
        if (kx == 2 && x0 == 56) *(uint*)&As[63][2 * ci2] = 0u;
      } else {
        const int c4 = t & 15, px4 = t >> 4;
#pragma unroll
        for (int p = 0; p < 4; ++p) {
          const int4 id = did[p]; const float4 wt = dwt[p];
          ushort h[4];
#pragma unroll
          for (int q = 0; q < 4; ++q) {
            const ushort* pl = inb_b + (size_t)(cib + c4 * 4 + q) * PLANE;
            float v = wt.x * bf2f(pl[id.x]) + wt.y * bf2f(pl[id.y]) +
                      wt.z * bf2f(pl[id.z]) + wt.w * bf2f(pl[id.w]);
            h[q] = f2bf(v);
          }
          uint2 pk = make_uint2((uint)h[0] | ((uint)h[1] << 16),
                                (uint)h[2] | ((uint)h[3] << 16));
          *(uint2*)&As[px4 * 4 + p][c4 * 4] = pk;
        }
      }
      __syncthreads();
      // ---------------- compute ----------------
      bf16x8 af[MFR][2];
#pragma unroll
      for (int mi = 0; mi < MFR; ++mi)
#pragma unroll
        for (int ks = 0; ks < 2; ++ks) {
          int cor = cob + wm * WM_SUB + mi * 16 + lm;
          if (CO_TILE == 32 && cor >= Cout) {
            bf16x8 z = {}; af[mi][ks] = z;
          } else {
            af[mi][ks] = *(const bf16x8*)(wg + ((size_t)kk * Cout + cor) * 256 +
                                          cib + ks * 32 + kg * 8);
          }
        }
      bf16x8 bfr[NFR][2];
#pragma unroll
      for (int ni = 0; ni < NFR; ++ni)
#pragma unroll
        for (int ks = 0; ks < 2; ++ks)
          bfr[ni][ks] = *(const bf16x8*)&As[wn * PX_SUB + ni * 16 + lm][ks * 32 + kg * 8];
#pragma unroll
      for (int mi = 0; mi < MFR; ++mi)
#pragma unroll
        for (int ni = 0; ni < NFR; ++ni)
#pragma unroll
          for (int ks = 0; ks < 2; ++ks)
            acc[mi][ni] = __builtin_amdgcn_mfma_f32_16x16x32_bf16(
                af[mi][ks], bfr[ni][ks], acc[mi][ni], 0, 0, 0);
      __syncthreads();
    }
  }
  // ---------------- epilogue ----------------
#pragma unroll
  for (int mi = 0; mi < MFR; ++mi)
#pragma unroll
    for (int ni = 0; ni < NFR; ++ni) {
      int px = wn * PX_SUB + ni * 16 + lm;
#pragma unroll
      for (int r = 0; r < 4; ++r) {
        int co = cob + wm * WM_SUB + mi * 16 + kg * 4 + r;
        if (CO_TILE == 32 && co >= Cout) continue;
        size_t o = ((size_t)(b * Cout + co)) * PLANE + y * 64 + px;
        if (OUT_BF16) ((ushort*)outp)[o] = f2bf(acc[mi][ni][r]);
        else          ((float*)outp)[o]  = acc[mi][ni][r];
      }
    }
}

// ---------------------------------------------------------------------------
// fp32 classification conv (Cout=15) reading bf16 input — numeric margin.
// ---------------------------------------------------------------------------
__global__ __launch_bounds__(256) void conv_cls(const ushort* __restrict__ inb,
                                                const float* __restrict__ w,
                                                float* __restrict__ out) {
  __shared__ float Asf[64][68];  // [ci][px]
  __shared__ float Wsf[64][16];  // [ci][co]
  const int y = blockIdx.x, b = blockIdx.y, t = threadIdx.x;
  const int px = t & 63, cq = t >> 6;
  float acc[4] = {0.f, 0.f, 0.f, 0.f};
  const ushort* inb_b = inb + (size_t)b * 256 * PLANE;
  for (int kk = 0; kk < 9; ++kk) {
    const int ky = kk / 3, kx = kk % 3;
    const int iy = y + ky - 1;
    if (iy < 0 || iy >= 64) continue;
    for (int cc = 0; cc < 4; ++cc) {
      const int cib = cc * 64;
      {
        const int ci = t >> 2, x0 = (t & 3) * 16;
        const ushort* r0 = inb_b + ((size_t)(cib + ci) * 64 + iy) * 64 + x0;
        uint4 v0 = *(const uint4*)r0;
        uint4 v1 = *(const uint4*)(r0 + 8);
        const ushort* h0 = (const ushort*)&v0;
        const ushort* h1 = (const ushort*)&v1;
#pragma unroll
        for (int j = 0; j < 16; ++j) {
          int pxw = x0 + j + 1 - kx;
          float v = (j < 8) ? bf2f(h0[j]) : bf2f(h1[j - 8]);
          if (pxw >= 0 && pxw < 64) Asf[ci][pxw] = v;
        }
        if (kx == 0 && x0 == 0)  Asf[ci][0] = 0.f;
        if (kx == 2 && x0 == 48) Asf[ci][63] = 0.f;
      }
      {
        const int co = t & 15, cb4 = (t >> 4) * 4;
#pragma unroll
        for (int q = 0; q < 4; ++q)
          Wsf[cb4 + q][co] =
              (co < 15) ? w[co * 2304 + (cib + cb4 + q) * 9 + kk] : 0.f;
      }
      __syncthreads();
#pragma unroll 4
      for (int ci = 0; ci < 64; ++ci) {
        float a = Asf[ci][px];
#pragma unroll
        for (int i = 0; i < 4; ++i) acc[i] += a * Wsf[ci][cq * 4 + i];
      }
      __syncthreads();
    }
  }
#pragma unroll
  for (int i = 0; i < 4; ++i) {
    int co = cq * 4 + i;
    if (co < 15)
      out[((size_t)(b * 15 + co)) * PLANE + y * 64 + px] = acc[i];
  }
}

// ---------------------------------------------------------------------------
// deform-conv bilinear tap tables (fp32 offsets in, torchvision v1 masking)
// ---------------------------------------------------------------------------
__global__ __launch_bounds__(256) void precomp_offsets(
    const float* __restrict__ off, int4* __restrict__ idx4,
    float4* __restrict__ wt4) {
  int tid = blockIdx.x * 256 + threadIdx.x;
  if (tid >= 4 * 9 * PLANE) return;
  int x = tid & 63, y = (tid >> 6) & 63;
  int kk = (tid >> 12) % 9;
  int b = tid / (9 * PLANE);
  float dy = off[((b * 18 + 2 * kk) * 64 + y) * 64 + x];
  float dx = off[((b * 18 + 2 * kk + 1) * 64 + y) * 64 + x];
  float sy = dy + (float)(y - 1 + kk / 3);
  float sx = dx + (float)(x - 1 + kk % 3);
  float y0f = floorf(sy), x0f = floorf(sx);
  float wy = sy - y0f, wx = sx - x0f;
  int y0 = (int)y0f, x0 = (int)x0f, y1 = y0 + 1, x1 = x0 + 1;
  float vy0 = ((unsigned)y0 < 64u) ? 1.f : 0.f;
  float vy1 = ((unsigned)y1 < 64u) ? 1.f : 0.f;
  float vx0 = ((unsigned)x0 < 64u) ? 1.f : 0.f;
  float vx1 = ((unsigned)x1 < 64u) ? 1.f : 0.f;
  int cy0 = min(max(y0, 0), 63), cy1 = min(max(y1, 0), 63);
  int cx0 = min(max(x0, 0), 63), cx1 = min(max(x1, 0), 63);
  idx4[tid] = make_int4(cy0 * 64 + cx0, cy0 * 64 + cx1,
                        cy1 * 64 + cx0, cy1 * 64 + cx1);
  wt4[tid] = make_float4((1.f - wy) * (1.f - wx) * vy0 * vx0,
                         (1.f - wy) * wx * vy0 * vx1,
                         wy * (1.f - wx) * vy1 * vx0, wy * wx * vy1 * vx1);
}

// ---------------------------------------------------------------------------
// GroupNorm on bf16 activations
// ---------------------------------------------------------------------------
__global__ __launch_bounds__(256) void gn_stats(const ushort* __restrict__ x,
                                                float2* __restrict__ stats) {
  int bg = blockIdx.x;
  const uint4* p = (const uint4*)(x + (size_t)bg * 32768);
  float s = 0.f, q = 0.f;
  for (int i = threadIdx.x; i < 4096; i += 256) {
    uint4 v = p[i];
    const ushort* h = (const ushort*)&v;
#pragma unroll
    for (int j = 0; j < 8; ++j) { float f = bf2f(h[j]); s += f; q += f * f; }
  }
#pragma unroll
  for (int o = 32; o; o >>= 1) { s += __shfl_xor(s, o); q += __shfl_xor(q, o); }
  __shared__ float ss[4], qq[4];
  int wid = threadIdx.x >> 6;
  if ((threadIdx.x & 63) == 0) { ss[wid] = s; qq[wid] = q; }
  __syncthreads();
  if (threadIdx.x == 0) {
    s = ss[0] + ss[1] + ss[2] + ss[3];
    q = qq[0] + qq[1] + qq[2] + qq[3];
    float m = s / 32768.f;
    float v = q / 32768.f - m * m;
    stats[bg] = make_float2(m, rsqrtf(v + 1e-5f));
  }
}

__global__ __launch_bounds__(256) void gn_apply(
    const ushort* __restrict__ x, const float2* __restrict__ stats,
    const float* __restrict__ gamma, const float* __restrict__ beta,
    ushort* __restrict__ out) {
  int i = blockIdx.x * 256 + threadIdx.x;  // uint4 index, 524288 total
  uint4 v = ((const uint4*)x)[i];
  int plane = i >> 9;
  int c = plane & 255;
  float2 st = stats[plane >> 3];
  float a = st.y * gamma[c];
  float bb = beta[c] - st.x * a;
  ushort* h = (ushort*)&v;
#pragma unroll
  for (int j = 0; j < 8; ++j) h[j] = f2bf(bf2f(h[j]) * a + bb);
  ((uint4*)out)[i] = v;
}

// ---------------------------------------------------------------------------
// weight prep: fp32 [Cout][ci*9+kk] -> bf16 tap-major [9][Cout][256]
// ---------------------------------------------------------------------------
struct WJobs {
  const float* src[11];
  ushort* dst[11];
  int cout[11];
};
__global__ __launch_bounds__(256) void wcvt(WJobs j) {
  int job = blockIdx.z, kk = blockIdx.y, co = blockIdx.x, ci = threadIdx.x;
  int Cout = j.cout[job];
  if (co >= Cout) return;
  j.dst[job][((size_t)kk * Cout + co) * 256 + ci] =
      f2bf(j.src[job][co * 2304 + ci * 9 + kk]);
}

__global__ __launch_bounds__(256) void fcvt(const float* __restrict__ src,
                                            ushort* __restrict__ dst, int n4) {
  int i = blockIdx.x * 256 + threadIdx.x;
  if (i >= n4) return;
  float4 v = ((const float4*)src)[i];
  ushort4 h;
  h.x = f2bf(v.x); h.y = f2bf(v.y); h.z = f2bf(v.z); h.w = f2bf(v.w);
  ((ushort4*)dst)[i] = h;
}

// ---------------------------------------------------------------------------
__global__ __launch_bounds__(256) void rp_out(const float* __restrict__ off1,
                                              const float* __restrict__ off2,
                                              float* __restrict__ out) {
  int tid = blockIdx.x * 256 + threadIdx.x;
  if (tid >= OFF_ELEMS) return;
  int x = tid & 63, y = (tid >> 6) & 63;
  int ch = (tid >> 12) % 18;
  int k = ch >> 1;
  float base = (ch & 1) ? (float)(x + (k % 3) - 1) : (float)(y + (k / 3) - 1);
  float r1 = base + off1[tid];
  out[tid] = r1;
  out[OFF_ELEMS + tid] = r1 + off2[tid];
}

// ---------------------------------------------------------------------------
extern "C" void kernel_launch(void* const* d_in, const int* in_sizes, int n_in,
                              void* d_out, int out_size, void* d_ws,
                              size_t ws_size, hipStream_t stream) {
  (void)in_sizes; (void)n_in; (void)out_size; (void)ws_size;
  const float* feature = (const float*)d_in[0];
  const float* loc_ws  = (const float*)d_in[1];
  const float* loc_g   = (const float*)d_in[2];
  const float* loc_b   = (const float*)d_in[3];
  const float* cls_ws  = (const float*)d_in[4];
  const float* cls_g   = (const float*)d_in[5];
  const float* cls_b   = (const float*)d_in[6];
  const float* pi_w    = (const float*)d_in[7];
  const float* pio_w   = (const float*)d_in[8];
  const float* prd_w   = (const float*)d_in[9];
  const float* pro_w   = (const float*)d_in[10];
  const float* cd_w    = (const float*)d_in[11];
  const float* co_w    = (const float*)d_in[12];
  float* out = (float*)d_out;

  char* p = (char*)d_ws;
  int4*   idx4 = (int4*)p;            p += 147456 * 16;
  float4* wt4  = (float4*)p;          p += 147456 * 16;
  ushort* feat_bf = (ushort*)p;       p += 4194304 * 2;
  ushort* wg      = (ushort*)p;       p += 9 * 589824 * 2;  // [9 tensors][9][256][256]
  ushort* wgpio   = (ushort*)p;       p += 41472 * 2;
  ushort* wgpro   = (ushort*)p;       p += 41472 * 2;
  ushort* actA    = (ushort*)p;       p += 4194304 * 2;
  ushort* actB    = (ushort*)p;       p += 4194304 * 2;
  float*  off1    = (float*)p;        p += OFF_ELEMS * 4;
  float*  off2    = (float*)p;        p += OFF_ELEMS * 4;
  float2* stats   = (float2*)p;

  // weight blocks inside wg: loc0,loc1,loc2,cls0,cls1,cls2,pi,prd,cd
  ushort* WG[9];
  for (int i = 0; i < 9; ++i) WG[i] = wg + (size_t)i * 589824;

  dim3 blk(256);
  // ---- convert weights + feature ----
  fcvt<<<dim3(4096), blk, 0, stream>>>(feature, feat_bf, 1048576);
  WJobs jobs;
  const float* srcs[11] = {loc_ws, loc_ws + 589824, loc_ws + 2 * 589824,
                           cls_ws, cls_ws + 589824, cls_ws + 2 * 589824,
                           pi_w,   prd_w,           cd_w,
                           pio_w,  pro_w};
  ushort* dsts[11] = {WG[0], WG[1], WG[2], WG[3], WG[4], WG[5],
                      WG[6], WG[7], WG[8], wgpio, wgpro};
  for (int i = 0; i < 11; ++i) {
    jobs.src[i] = srcs[i];
    jobs.dst[i] = dsts[i];
    jobs.cout[i] = (i < 9) ? 256 : 18;
  }
  wcvt<<<dim3(256, 9, 11), blk, 0, stream>>>(jobs);

  auto conv = [&](const ushort* in, const ushort* w, ushort* o) {
    conv_mfma<128, false, true><<<dim3(64, 2, 4), blk, 0, stream>>>(
        in, w, o, 256, nullptr, nullptr);
  };
  auto dconv = [&](const ushort* in, const ushort* w, ushort* o) {
    conv_mfma<128, true, true><<<dim3(64, 2, 4), blk, 0, stream>>>(
        in, w, o, 256, idx4, wt4);
  };
  auto sconv = [&](const ushort* in, const ushort* w, float* o) {
    conv_mfma<32, false, false><<<dim3(64, 1, 4), blk, 0, stream>>>(
        in, w, o, 18, nullptr, nullptr);
  };
  auto gn = [&](const ushort* in, const float* g, const float* b, ushort* o) {
    gn_stats<<<dim3(128), blk, 0, stream>>>(in, stats);
    gn_apply<<<dim3(2048), blk, 0, stream>>>(in, stats, g, b, o);
  };

  // ---- loc branch ----
  conv(feat_bf, WG[0], actA);
  gn(actA, loc_g + 0,   loc_b + 0,   actB);
  conv(actB, WG[1], actA);
  gn(actA, loc_g + 256, loc_b + 256, actB);
  conv(actB, WG[2], actA);
  gn(actA, loc_g + 512, loc_b + 512, actB);       // actB = loc
  conv(actB, WG[6], actA);                        // pi
  sconv(actA, wgpio, off1);                       // offset1
  precomp_offsets<<<dim3(576), blk, 0, stream>>>(off1, idx4, wt4);
  dconv(actB, WG[7], actA);                       // deform(loc)
  sconv(actA, wgpro, off2);                       // offset2

  // ---- cls branch ----
  conv(feat_bf, WG[3], actA);
  gn(actA, cls_g + 0,   cls_b + 0,   actB);
  conv(actB, WG[4], actA);
  gn(actA, cls_g + 256, cls_b + 256, actB);
  conv(actB, WG[5], actA);
  gn(actA, cls_g + 512, cls_b + 512, actB);       // actB = clsf
  dconv(actB, WG[8], actA);                       // deform(clsf)
  conv_cls<<<dim3(64, 4), blk, 0, stream>>>(actA, co_w, out + CLS_OFF);

  // ---- rep points ----
  rp_out<<<dim3(1152), blk, 0, stream>>>(off1, off2, out);
}

// Round 4
// 1375.622 us; speedup vs baseline: 3.8758x; 1.9363x over previous
//
#include <hip/hip_runtime.h>

#define PLANE 4096
#define OFF_ELEMS 294912
#define CLS_OFF   589824

typedef __attribute__((ext_vector_type(4))) float f32x4;
typedef __attribute__((ext_vector_type(8))) short bf16x8;

__device__ __forceinline__ float bf2f(ushort u) {
  union { uint u; float f; } x; x.u = ((uint)u) << 16; return x.f;
}
__device__ __forceinline__ ushort f2bf(float f) {
  union { float f; uint u; } x; x.f = f;
  return (ushort)((x.u + 0x7fffu + ((x.u >> 16) & 1u)) >> 16);
}

// ---------------------------------------------------------------------------
// NHWC bf16 MFMA conv3x3 (pad 1), no LDS, no barriers.
// GEMM per tap: D[co][px] += W_kk[co][ci] * X[(y+ky-1)(px+kx-1)][ci].
// A-frags: tap-major W [9][Cout][256], 16B contiguous per lane.
// B-frags: NHWC input, 16B contiguous per lane; border -> cndmask zero.
// DEFORM: B-frag = bilinear blend of 4 contiguous 16B gathers (precomp table).
// ---------------------------------------------------------------------------
template <int CO_TILE, bool DEFORM, bool OUT_BF16>
__global__ __launch_bounds__(256) void conv_nhwc(
    const ushort* __restrict__ in, const ushort* __restrict__ wg,
    void* __restrict__ outp, int Cout,
    const int4* __restrict__ idx4, const float4* __restrict__ wt4) {
  constexpr int WM_WAVES = (CO_TILE == 128) ? 2 : 1;
  constexpr int WM_SUB = CO_TILE / WM_WAVES;   // 64 or 32
  constexpr int MFR = WM_SUB / 16;             // 4 or 2
  constexpr int WN_WAVES = 4 / WM_WAVES;       // 2 or 4
  constexpr int PX_SUB = 64 / WN_WAVES;        // 32 or 16
  constexpr int NFR = PX_SUB / 16;             // 2 or 1

  const int y = blockIdx.x, b = blockIdx.z;
  const int cob = blockIdx.y * CO_TILE;
  const int t = threadIdx.x;
  const int wv = t >> 6, lane = t & 63, lm = lane & 15, kg = lane >> 4;
  const int wm = (WM_WAVES == 2) ? (wv & 1) : 0;
  const int wn = (WM_WAVES == 2) ? (wv >> 1) : wv;

  f32x4 acc[MFR][NFR] = {};
  const ushort* inb = in + (size_t)b * (PLANE * 256);

  const ushort* wrow[MFR];
#pragma unroll
  for (int mi = 0; mi < MFR; ++mi) {
    int cor = cob + wm * WM_SUB + mi * 16 + lm;
    if (cor > Cout - 1) cor = Cout - 1;   // clamped rows land in D rows >= Cout (unstored)
    wrow[mi] = wg + (size_t)cor * 256 + kg * 8;
  }
  const int wks = Cout * 256;

  bf16x8 Aa[MFR][2], Ab[MFR][2], Ba[NFR][2], Bb[NFR][2];

  for (int kk = 0; kk < 9; ++kk) {
    const int ky = kk / 3, kx = kk - ky * 3;
    const int wko = kk * wks;
    const ushort* pB[NFR]; bool bval[NFR];
    int4 did[NFR]; float4 dwt[NFR];
    if (!DEFORM) {
      const int iy = y + ky - 1;
      const bool vy = (unsigned)iy < 64u;
      const int iyc = vy ? iy : 0;
#pragma unroll
      for (int ni = 0; ni < NFR; ++ni) {
        int px = wn * PX_SUB + ni * 16 + lm;
        int ix = px + kx - 1;
        bool v = vy && ((unsigned)ix < 64u);
        bval[ni] = v;
        pB[ni] = inb + ((size_t)(iyc * 64 + (v ? ix : 0))) * 256 + kg * 8;
      }
    } else {
#pragma unroll
      for (int ni = 0; ni < NFR; ++ni) {
        int px = wn * PX_SUB + ni * 16 + lm;
        int pi = ((b * 9 + kk) * 64 + y) * 64 + px;
        did[ni] = idx4[pi]; dwt[ni] = wt4[pi];
      }
    }
    auto loadA = [&](bf16x8 (&A)[MFR][2], int cc) {
#pragma unroll
      for (int mi = 0; mi < MFR; ++mi)
#pragma unroll
        for (int ks = 0; ks < 2; ++ks)
          A[mi][ks] = *(const bf16x8*)(wrow[mi] + wko + cc * 64 + ks * 32);
    };
    auto loadB = [&](bf16x8 (&B)[NFR][2], int cc) {
      if (!DEFORM) {
        bf16x8 z = {};
#pragma unroll
        for (int ni = 0; ni < NFR; ++ni)
#pragma unroll
          for (int ks = 0; ks < 2; ++ks) {
            bf16x8 r = *(const bf16x8*)(pB[ni] + cc * 64 + ks * 32);
            B[ni][ks] = bval[ni] ? r : z;
          }
      } else {
#pragma unroll
        for (int ni = 0; ni < NFR; ++ni)
#pragma unroll
          for (int ks = 0; ks < 2; ++ks) {
            const ushort* cb = inb + cc * 64 + ks * 32 + kg * 8;
            bf16x8 p0 = *(const bf16x8*)(cb + (size_t)did[ni].x * 256);
            bf16x8 p1 = *(const bf16x8*)(cb + (size_t)did[ni].y * 256);
            bf16x8 p2 = *(const bf16x8*)(cb + (size_t)did[ni].z * 256);
            bf16x8 p3 = *(const bf16x8*)(cb + (size_t)did[ni].w * 256);
            bf16x8 r;
#pragma unroll
            for (int j = 0; j < 8; ++j) {
              float f = dwt[ni].x * bf2f(((ushort*)&p0)[j])
                      + dwt[ni].y * bf2f(((ushort*)&p1)[j])
                      + dwt[ni].z * bf2f(((ushort*)&p2)[j])
                      + dwt[ni].w * bf2f(((ushort*)&p3)[j]);
              ((ushort*)&r)[j] = f2bf(f);
            }
            B[ni][ks] = r;
          }
      }
    };
    auto mma = [&](bf16x8 (&A)[MFR][2], bf16x8 (&B)[NFR][2]) {
      __builtin_amdgcn_s_setprio(1);
#pragma unroll
      for (int mi = 0; mi < MFR; ++mi)
#pragma unroll
        for (int ni = 0; ni < NFR; ++ni)
#pragma unroll
          for (int ks = 0; ks < 2; ++ks)
            acc[mi][ni] = __builtin_amdgcn_mfma_f32_16x16x32_bf16(
                A[mi][ks], B[ni][ks], acc[mi][ni], 0, 0, 0);
      __builtin_amdgcn_s_setprio(0);
    };
    // 1-deep register double-buffer over the 4 ci-chunks
    loadA(Aa, 0); loadB(Ba, 0);
    loadA(Ab, 1); loadB(Bb, 1);
    mma(Aa, Ba);
    loadA(Aa, 2); loadB(Ba, 2);
    mma(Ab, Bb);
    loadA(Ab, 3); loadB(Bb, 3);
    mma(Aa, Ba);
    mma(Ab, Bb);
  }
  // ---------------- epilogue ----------------
  if (OUT_BF16) {
    ushort* outb = (ushort*)outp + (size_t)b * (PLANE * 256) + (size_t)y * 64 * 256;
#pragma unroll
    for (int mi = 0; mi < MFR; ++mi)
#pragma unroll
      for (int ni = 0; ni < NFR; ++ni) {
        int px = wn * PX_SUB + ni * 16 + lm;
        int co0 = cob + wm * WM_SUB + mi * 16 + kg * 4;
        ushort4 h;
        h.x = f2bf(acc[mi][ni][0]); h.y = f2bf(acc[mi][ni][1]);
        h.z = f2bf(acc[mi][ni][2]); h.w = f2bf(acc[mi][ni][3]);
        *(ushort4*)(outb + (size_t)px * 256 + co0) = h;
      }
  } else {
    float* o = (float*)outp;
#pragma unroll
    for (int mi = 0; mi < MFR; ++mi)
#pragma unroll
      for (int ni = 0; ni < NFR; ++ni) {
        int px = wn * PX_SUB + ni * 16 + lm;
#pragma unroll
        for (int r = 0; r < 4; ++r) {
          int co = cob + wm * WM_SUB + mi * 16 + kg * 4 + r;
          if (co < Cout)
            o[((size_t)(b * Cout + co)) * PLANE + y * 64 + px] = acc[mi][ni][r];
        }
      }
  }
}

// ---------------------------------------------------------------------------
// fp32 NCHW feature -> bf16 NHWC (LDS tile transpose, one row per block)
// ---------------------------------------------------------------------------
__global__ __launch_bounds__(256) void tr_nhwc(const float* __restrict__ src,
                                               ushort* __restrict__ dst) {
  __shared__ ushort T[64][264];  // row stride 528B = 33*16B (aligned, staggered banks)
  int y = blockIdx.x, b = blockIdx.y, t = threadIdx.x;
  const float* s = src + (size_t)b * 1048576 + y * 64;
  int ci0 = t >> 2, f4 = t & 3;
#pragma unroll
  for (int cb = 0; cb < 4; ++cb) {
    int ci = cb * 64 + ci0;
#pragma unroll
    for (int l = 0; l < 4; ++l) {
      int px = (f4 + l * 4) * 4;
      float4 v = *(const float4*)(s + (size_t)ci * 4096 + px);
      T[px + 0][ci] = f2bf(v.x);
      T[px + 1][ci] = f2bf(v.y);
      T[px + 2][ci] = f2bf(v.z);
      T[px + 3][ci] = f2bf(v.w);
    }
  }
  __syncthreads();
  ushort* d = dst + (size_t)(b * 4096 + y * 64) * 256;
#pragma unroll
  for (int k = 0; k < 8; ++k) {
    int u = t + k * 256;
    int px = u >> 5, c32 = u & 31;
    uint4 vv = *(const uint4*)&T[px][c32 * 8];
    *(uint4*)(d + (size_t)px * 256 + c32 * 8) = vv;
  }
}

// ---------------------------------------------------------------------------
// deform-conv bilinear tap tables (fp32 NCHW offsets in, torchvision v1)
// ---------------------------------------------------------------------------
__global__ __launch_bounds__(256) void precomp_offsets(
    const float* __restrict__ off, int4* __restrict__ idx4,
    float4* __restrict__ wt4) {
  int tid = blockIdx.x * 256 + threadIdx.x;
  if (tid >= 4 * 9 * PLANE) return;
  int x = tid & 63, y = (tid >> 6) & 63;
  int kk = (tid >> 12) % 9;
  int b = tid / (9 * PLANE);
  float dy = off[((b * 18 + 2 * kk) * 64 + y) * 64 + x];
  float dx = off[((b * 18 + 2 * kk + 1) * 64 + y) * 64 + x];
  float sy = dy + (float)(y - 1 + kk / 3);
  float sx = dx + (float)(x - 1 + kk % 3);
  float y0f = floorf(sy), x0f = floorf(sx);
  float wy = sy - y0f, wx = sx - x0f;
  int y0 = (int)y0f, x0 = (int)x0f, y1 = y0 + 1, x1 = x0 + 1;
  float vy0 = ((unsigned)y0 < 64u) ? 1.f : 0.f;
  float vy1 = ((unsigned)y1 < 64u) ? 1.f : 0.f;
  float vx0 = ((unsigned)x0 < 64u) ? 1.f : 0.f;
  float vx1 = ((unsigned)x1 < 64u) ? 1.f : 0.f;
  int cy0 = min(max(y0, 0), 63), cy1 = min(max(y1, 0), 63);
  int cx0 = min(max(x0, 0), 63), cx1 = min(max(x1, 0), 63);
  idx4[tid] = make_int4(cy0 * 64 + cx0, cy0 * 64 + cx1,
                        cy1 * 64 + cx0, cy1 * 64 + cx1);
  wt4[tid] = make_float4((1.f - wy) * (1.f - wx) * vy0 * vx0,
                         (1.f - wy) * wx * vy0 * vx1,
                         wy * (1.f - wx) * vy1 * vx0, wy * wx * vy1 * vx1);
}

// ---------------------------------------------------------------------------
// GroupNorm on NHWC bf16 (group = 8 contiguous channels = one uint4)
// ---------------------------------------------------------------------------
__global__ __launch_bounds__(256) void gn_stats(const ushort* __restrict__ x,
                                                float2* __restrict__ stats) {
  int bg = blockIdx.x;           // b*32+g
  int b = bg >> 5, g = bg & 31;
  const uint4* base = (const uint4*)(x + (size_t)b * 1048576 + g * 8);
  float s = 0.f, q = 0.f;
#pragma unroll
  for (int k = 0; k < 16; ++k) {
    int p = threadIdx.x + k * 256;
    uint4 v = base[(size_t)p * 32];
    const ushort* h = (const ushort*)&v;
#pragma unroll
    for (int j = 0; j < 8; ++j) { float f = bf2f(h[j]); s += f; q += f * f; }
  }
#pragma unroll
  for (int o = 32; o; o >>= 1) { s += __shfl_xor(s, o); q += __shfl_xor(q, o); }
  __shared__ float ss[4], qq[4];
  int wid = threadIdx.x >> 6;
  if ((threadIdx.x & 63) == 0) { ss[wid] = s; qq[wid] = q; }
  __syncthreads();
  if (threadIdx.x == 0) {
    s = ss[0] + ss[1] + ss[2] + ss[3];
    q = qq[0] + qq[1] + qq[2] + qq[3];
    float m = s / 32768.f;
    float v = q / 32768.f - m * m;
    stats[bg] = make_float2(m, rsqrtf(v + 1e-5f));
  }
}

__global__ __launch_bounds__(256) void gn_apply(
    const ushort* __restrict__ x, const float2* __restrict__ stats,
    const float* __restrict__ gamma, const float* __restrict__ beta,
    ushort* __restrict__ out) {
  int i = blockIdx.x * 256 + threadIdx.x;  // uint4 index, 524288 total
  uint4 v = ((const uint4*)x)[i];
  int cg = i & 31;                         // channel-oct == group id
  int b = i >> 17;
  float2 st = stats[b * 32 + cg];
  const float4* gp = (const float4*)(gamma + cg * 8);
  const float4* bp = (const float4*)(beta + cg * 8);
  float4 g0 = gp[0], g1 = gp[1], b0 = bp[0], b1 = bp[1];
  float ga[8] = {g0.x, g0.y, g0.z, g0.w, g1.x, g1.y, g1.z, g1.w};
  float bb[8] = {b0.x, b0.y, b0.z, b0.w, b1.x, b1.y, b1.z, b1.w};
  ushort* h = (ushort*)&v;
#pragma unroll
  for (int j = 0; j < 8; ++j) {
    float a = st.y * ga[j];
    h[j] = f2bf(bf2f(h[j]) * a + (bb[j] - st.x * a));
  }
  ((uint4*)out)[i] = v;
}

// ---------------------------------------------------------------------------
// weight prep: fp32 [Cout][ci*9+kk] -> bf16 tap-major [9][Cout][256]
// ---------------------------------------------------------------------------
struct WJobs {
  const float* src[12];
  ushort* dst[12];
  int cout[12];
};
__global__ __launch_bounds__(256) void wcvt(WJobs j) {
  int job = blockIdx.z, kk = blockIdx.y, co = blockIdx.x, ci = threadIdx.x;
  int Cout = j.cout[job];
  if (co >= Cout) return;
  j.dst[job][((size_t)kk * Cout + co) * 256 + ci] =
      f2bf(j.src[job][co * 2304 + ci * 9 + kk]);
}

// ---------------------------------------------------------------------------
__global__ __launch_bounds__(256) void rp_out(const float* __restrict__ off1,
                                              const float* __restrict__ off2,
                                              float* __restrict__ out) {
  int tid = blockIdx.x * 256 + threadIdx.x;
  if (tid >= OFF_ELEMS) return;
  int x = tid & 63, y = (tid >> 6) & 63;
  int ch = (tid >> 12) % 18;
  int k = ch >> 1;
  float base = (ch & 1) ? (float)(x + (k % 3) - 1) : (float)(y + (k / 3) - 1);
  float r1 = base + off1[tid];
  out[tid] = r1;
  out[OFF_ELEMS + tid] = r1 + off2[tid];
}

// ---------------------------------------------------------------------------
extern "C" void kernel_launch(void* const* d_in, const int* in_sizes, int n_in,
                              void* d_out, int out_size, void* d_ws,
                              size_t ws_size, hipStream_t stream) {
  (void)in_sizes; (void)n_in; (void)out_size; (void)ws_size;
  const float* feature = (const float*)d_in[0];
  const float* loc_ws  = (const float*)d_in[1];
  const float* loc_g   = (const float*)d_in[2];
  const float* loc_b   = (const float*)d_in[3];
  const float* cls_ws  = (const float*)d_in[4];
  const float* cls_g   = (const float*)d_in[5];
  const float* cls_b   = (const float*)d_in[6];
  const float* pi_w    = (const float*)d_in[7];
  const float* pio_w   = (const float*)d_in[8];
  const float* prd_w   = (const float*)d_in[9];
  const float* pro_w   = (const float*)d_in[10];
  const float* cd_w    = (const float*)d_in[11];
  const float* co_w    = (const float*)d_in[12];
  float* out = (float*)d_out;

  char* p = (char*)d_ws;
  int4*   idx4 = (int4*)p;            p += 147456 * 16;
  float4* wt4  = (float4*)p;          p += 147456 * 16;
  ushort* feat_bf = (ushort*)p;       p += 4194304 * 2;
  ushort* wg      = (ushort*)p;       p += 9 * 589824 * 2;  // 9x [9][256][256]
  ushort* wgpio   = (ushort*)p;       p += 41472 * 2;
  ushort* wgpro   = (ushort*)p;       p += 41472 * 2;
  ushort* wgco    = (ushort*)p;       p += 34560 * 2;
  ushort* actA    = (ushort*)p;       p += 4194304 * 2;
  ushort* actB    = (ushort*)p;       p += 4194304 * 2;
  float*  off1    = (float*)p;        p += OFF_ELEMS * 4;
  float*  off2    = (float*)p;        p += OFF_ELEMS * 4;
  float2* stats   = (float2*)p;

  ushort* WG[9];
  for (int i = 0; i < 9; ++i) WG[i] = wg + (size_t)i * 589824;

  dim3 blk(256);
  tr_nhwc<<<dim3(64, 4), blk, 0, stream>>>(feature, feat_bf);
  WJobs jobs;
  const float* srcs[12] = {loc_ws, loc_ws + 589824, loc_ws + 2 * 589824,
                           cls_ws, cls_ws + 589824, cls_ws + 2 * 589824,
                           pi_w,   prd_w,           cd_w,
                           pio_w,  pro_w,           co_w};
  ushort* dsts[12] = {WG[0], WG[1], WG[2], WG[3], WG[4], WG[5],
                      WG[6], WG[7], WG[8], wgpio, wgpro, wgco};
  int couts[12] = {256,256,256,256,256,256,256,256,256,18,18,15};
  for (int i = 0; i < 12; ++i) {
    jobs.src[i] = srcs[i]; jobs.dst[i] = dsts[i]; jobs.cout[i] = couts[i];
  }
  wcvt<<<dim3(256, 9, 12), blk, 0, stream>>>(jobs);

  auto conv = [&](const ushort* in, const ushort* w, ushort* o) {
    conv_nhwc<128, false, true><<<dim3(64, 2, 4), blk, 0, stream>>>(
        in, w, o, 256, nullptr, nullptr);
  };
  auto dconv = [&](const ushort* in, const ushort* w, ushort* o) {
    conv_nhwc<128, true, true><<<dim3(64, 2, 4), blk, 0, stream>>>(
        in, w, o, 256, idx4, wt4);
  };
  auto sconv = [&](const ushort* in, const ushort* w, float* o, int Cout) {
    conv_nhwc<32, false, false><<<dim3(64, 1, 4), blk, 0, stream>>>(
        in, w, o, Cout, nullptr, nullptr);
  };
  auto gn = [&](const ushort* in, const float* g, const float* b, ushort* o) {
    gn_stats<<<dim3(128), blk, 0, stream>>>(in, stats);
    gn_apply<<<dim3(2048), blk, 0, stream>>>(in, stats, g, b, o);
  };

  // ---- loc branch ----
  conv(feat_bf, WG[0], actA);
  gn(actA, loc_g + 0,   loc_b + 0,   actB);
  conv(actB, WG[1], actA);
  gn(actA, loc_g + 256, loc_b + 256, actB);
  conv(actB, WG[2], actA);
  gn(actA, loc_g + 512, loc_b + 512, actB);       // actB = loc (NHWC)
  conv(actB, WG[6], actA);                        // pi
  sconv(actA, wgpio, off1, 18);                   // offset1 (fp32 NCHW)
  precomp_offsets<<<dim3(576), blk, 0, stream>>>(off1, idx4, wt4);
  dconv(actB, WG[7], actA);                       // deform(loc, offset1)
  sconv(actA, wgpro, off2, 18);                   // offset2

  // ---- cls branch ----
  conv(feat_bf, WG[3], actA);
  gn(actA, cls_g + 0,   cls_b + 0,   actB);
  conv(actB, WG[4], actA);
  gn(actA, cls_g + 256, cls_b + 256, actB);
  conv(actB, WG[5], actA);
  gn(actA, cls_g + 512, cls_b + 512, actB);       // actB = clsf
  dconv(actB, WG[8], actA);                       // deform(clsf, offset1)
  sconv(actA, wgco, out + CLS_OFF, 15);           // classification (fp32 NCHW)

  // ---- rep points ----
  rp_out<<<dim3(1152), blk, 0, stream>>>(off1, off2, out);
}

// Round 5
// 1004.067 us; speedup vs baseline: 5.3100x; 1.3701x over previous
//
#include <hip/hip_runtime.h>

#define PLANE 4096
#define OFF_ELEMS 294912
#define CLS_OFF   589824

typedef __attribute__((ext_vector_type(4))) float f32x4;
typedef __attribute__((ext_vector_type(8))) short bf16x8;

__device__ __forceinline__ float bf2f(ushort u) {
  union { uint u; float f; } x; x.u = ((uint)u) << 16; return x.f;
}
__device__ __forceinline__ ushort f2bf(float f) {
  union { float f; uint u; } x; x.f = f;
  return (ushort)((x.u + 0x7fffu + ((x.u >> 16) & 1u)) >> 16);
}
__device__ __forceinline__ void gload_lds16(const void* g, void* l) {
  __builtin_amdgcn_global_load_lds(
      (const __attribute__((address_space(1))) void*)g,
      (__attribute__((address_space(3))) void*)l, 16, 0, 0);
}

// ---------------------------------------------------------------------------
// Staged NHWC bf16 MFMA conv3x3 (pad 1).  One block = one output row, all
// CO_TILE channels.  3 input rows (96 KB) staged to LDS via global_load_lds
// with granule XOR-swizzle (bank-conflict-free b128 reads).  A (weights,
// tap-major [9][Cout][256]) streamed from L2.  Grid 256 = (64 rows x 4 b),
// XCD-bijective swizzle: each XCD owns 32 contiguous rows of one batch.
// ---------------------------------------------------------------------------
template <int CO_TILE, bool OUT_BF16>
__global__ __launch_bounds__((CO_TILE == 256) ? 512 : 256, (CO_TILE == 256) ? 2 : 1)
void conv_std(const ushort* __restrict__ in, const ushort* __restrict__ wg,
              void* __restrict__ outp, int Cout) {
  constexpr int WAVES = (CO_TILE == 256) ? 8 : 4;
  constexpr int WM_WAVES = (CO_TILE == 256) ? 4 : 1;
  constexpr int WN_WAVES = WAVES / WM_WAVES;       // 2 or 4
  constexpr int WM_SUB = CO_TILE / WM_WAVES;       // 64 or 32
  constexpr int MFR = WM_SUB / 16;                 // 4 or 2
  constexpr int PX_SUB = 64 / WN_WAVES;            // 32 or 16
  constexpr int NFR = PX_SUB / 16;                 // 2 or 1
  constexpr int ISS = 96 / WAVES;                  // stage issues per wave

  __shared__ __align__(16) ushort Bs[49152];       // [3 rows][64 px][256 ci] 96 KB

  const int bid = blockIdx.x;
  const int r8 = bid & 7;
  const int b = r8 >> 1;
  const int y = (r8 & 1) * 32 + (bid >> 3);
  const int t = threadIdx.x;
  const int wv = t >> 6, lane = t & 63, lm = lane & 15, kg = lane >> 4;
  const int wm = (WM_WAVES == 4) ? (wv & 3) : 0;
  const int wn = (WM_WAVES == 4) ? (wv >> 2) : wv;

  const ushort* inb = in + (size_t)b * (PLANE * 256);

  // ---- stage 3 rows -> LDS (linear dest, inverse-swizzled global source) ----
  {
    const int pxl = lane >> 5;        // 0..1
    const int gd = lane & 31;         // dest granule
#pragma unroll
    for (int n = 0; n < ISS; ++n) {
      int i = wv * ISS + n;           // 0..95 ; row = i>>5, px0 = (i&31)*2
      int row = i >> 5;
      int iy = y + row - 1;
      if ((unsigned)iy < 64u) {
        int px = (i & 31) * 2 + pxl;
        int gs = gd ^ (px & 7);
        gload_lds16(inb + ((size_t)(iy * 64 + px)) * 256 + gs * 8,
                    (char*)Bs + i * 1024);
      }
    }
  }
  asm volatile("s_waitcnt vmcnt(0)" ::: "memory");
  __syncthreads();

  // ---- compute ----
  f32x4 acc[MFR][NFR] = {};
  const ushort* wrow[MFR];
#pragma unroll
  for (int mi = 0; mi < MFR; ++mi) {
    int cor = wm * WM_SUB + mi * 16 + lm;
    if (cor > Cout - 1) cor = Cout - 1;
    wrow[mi] = wg + (size_t)cor * 256 + kg * 8;
  }
  const int wks = Cout * 256;

  for (int kk = 0; kk < 9; ++kk) {
    const int ky = kk / 3, kx = kk - ky * 3;
    const int iy = y + ky - 1;
    if ((unsigned)iy >= 64u) continue;
    int rb[NFR], swz[NFR];
    bool bval[NFR];
#pragma unroll
    for (int ni = 0; ni < NFR; ++ni) {
      int px = wn * PX_SUB + ni * 16 + lm;
      int ix = px + kx - 1;
      bval[ni] = (unsigned)ix < 64u;
      int ixc = min(max(ix, 0), 63);
      rb[ni] = (ky * 64 + ixc) * 512;
      swz[ni] = ixc & 7;
    }
#pragma unroll
    for (int cc = 0; cc < 4; ++cc) {
      bf16x8 af[MFR][2], bf[NFR][2];
#pragma unroll
      for (int mi = 0; mi < MFR; ++mi)
#pragma unroll
        for (int ks = 0; ks < 2; ++ks)
          af[mi][ks] = *(const bf16x8*)(wrow[mi] + kk * wks + cc * 64 + ks * 32);
      bf16x8 z = {};
#pragma unroll
      for (int ni = 0; ni < NFR; ++ni)
#pragma unroll
        for (int ks = 0; ks < 2; ++ks) {
          int g = (cc * 8 + ks * 4 + kg) ^ swz[ni];
          bf16x8 v = *(const bf16x8*)((const char*)Bs + rb[ni] + g * 16);
          bf[ni][ks] = bval[ni] ? v : z;
        }
      __builtin_amdgcn_s_setprio(1);
#pragma unroll
      for (int mi = 0; mi < MFR; ++mi)
#pragma unroll
        for (int ni = 0; ni < NFR; ++ni)
#pragma unroll
          for (int ks = 0; ks < 2; ++ks)
            acc[mi][ni] = __builtin_amdgcn_mfma_f32_16x16x32_bf16(
                af[mi][ks], bf[ni][ks], acc[mi][ni], 0, 0, 0);
      __builtin_amdgcn_s_setprio(0);
    }
  }
  // ---- epilogue ----
  if (OUT_BF16) {
    ushort* outb = (ushort*)outp + (size_t)b * (PLANE * 256) + (size_t)y * 64 * 256;
#pragma unroll
    for (int mi = 0; mi < MFR; ++mi)
#pragma unroll
      for (int ni = 0; ni < NFR; ++ni) {
        int px = wn * PX_SUB + ni * 16 + lm;
        int co0 = wm * WM_SUB + mi * 16 + kg * 4;
        ushort4 h;
        h.x = f2bf(acc[mi][ni][0]); h.y = f2bf(acc[mi][ni][1]);
        h.z = f2bf(acc[mi][ni][2]); h.w = f2bf(acc[mi][ni][3]);
        *(ushort4*)(outb + (size_t)px * 256 + co0) = h;
      }
  } else {
    float* o = (float*)outp;
#pragma unroll
    for (int mi = 0; mi < MFR; ++mi)
#pragma unroll
      for (int ni = 0; ni < NFR; ++ni) {
        int px = wn * PX_SUB + ni * 16 + lm;
#pragma unroll
        for (int rr = 0; rr < 4; ++rr) {
          int co = wm * WM_SUB + mi * 16 + kg * 4 + rr;
          if (co < Cout)
            o[((size_t)(b * Cout + co)) * PLANE + y * 64 + px] = acc[mi][ni][rr];
        }
      }
  }
}

// ---------------------------------------------------------------------------
// Deformable conv3x3 (v1): same block structure; B-tile built per 64-ci chunk
// by in-kernel bilinear blend (4 contiguous 16B gathers) into swizzled LDS.
// ---------------------------------------------------------------------------
__global__ __launch_bounds__(512, 2) void conv_dfm(
    const ushort* __restrict__ in, const ushort* __restrict__ wg,
    ushort* __restrict__ outp, const int4* __restrict__ idx4,
    const float4* __restrict__ wt4) {
  __shared__ __align__(16) ushort Ds[36864];  // [9 kk][64 px][64 ci] 72 KB

  const int bid = blockIdx.x;
  const int r8 = bid & 7;
  const int b = r8 >> 1;
  const int y = (r8 & 1) * 32 + (bid >> 3);
  const int t = threadIdx.x;
  const int wv = t >> 6, lane = t & 63, lm = lane & 15, kg = lane >> 4;
  const int wm = wv & 3, wn = wv >> 2;

  const ushort* inb = in + (size_t)b * (PLANE * 256);

  // hoist tables: thread t owns granule (kk=n, px=t>>3, gd=t&7) for all chunks
  const int spx = t >> 3, gd = t & 7, gs = gd ^ (spx & 7);
  int4 did[9]; float4 dwt[9];
#pragma unroll
  for (int n = 0; n < 9; ++n) {
    int pi = ((b * 9 + n) * 64 + y) * 64 + spx;
    did[n] = idx4[pi]; dwt[n] = wt4[pi];
  }

  f32x4 acc[4][2] = {};
  const ushort* wrow[4];
#pragma unroll
  for (int mi = 0; mi < 4; ++mi)
    wrow[mi] = wg + (size_t)(wm * 64 + mi * 16 + lm) * 256 + kg * 8;

  int pxn[2];
#pragma unroll
  for (int ni = 0; ni < 2; ++ni) pxn[ni] = wn * 32 + ni * 16 + lm;

  for (int cc = 0; cc < 4; ++cc) {
    // ---- stage: blend 9 granules into swizzled LDS ----
#pragma unroll
    for (int n = 0; n < 9; ++n) {
      const ushort* cb = inb + cc * 64 + gs * 8;
      bf16x8 p0 = *(const bf16x8*)(cb + (size_t)did[n].x * 256);
      bf16x8 p1 = *(const bf16x8*)(cb + (size_t)did[n].y * 256);
      bf16x8 p2 = *(const bf16x8*)(cb + (size_t)did[n].z * 256);
      bf16x8 p3 = *(const bf16x8*)(cb + (size_t)did[n].w * 256);
      uint4 pk;
      ushort* hp = (ushort*)&pk;
#pragma unroll
      for (int j = 0; j < 8; ++j) {
        float f = dwt[n].x * bf2f(((ushort*)&p0)[j])
                + dwt[n].y * bf2f(((ushort*)&p1)[j])
                + dwt[n].z * bf2f(((ushort*)&p2)[j])
                + dwt[n].w * bf2f(((ushort*)&p3)[j]);
        hp[j] = f2bf(f);
      }
      *(uint4*)((char*)Ds + (n * 64 + spx) * 128 + gd * 16) = pk;
    }
    __syncthreads();
    // ---- compute this 64-ci chunk over all 9 taps ----
    for (int kk = 0; kk < 9; ++kk) {
      bf16x8 af[4][2], bf[2][2];
#pragma unroll
      for (int mi = 0; mi < 4; ++mi)
#pragma unroll
        for (int ks = 0; ks < 2; ++ks)
          af[mi][ks] = *(const bf16x8*)(wrow[mi] + kk * 65536 + cc * 64 + ks * 32);
#pragma unroll
      for (int ni = 0; ni < 2; ++ni)
#pragma unroll
        for (int ks = 0; ks < 2; ++ks) {
          int g = (ks * 4 + kg) ^ (pxn[ni] & 7);
          bf[ni][ks] = *(const bf16x8*)((const char*)Ds +
                                        (kk * 64 + pxn[ni]) * 128 + g * 16);
        }
      __builtin_amdgcn_s_setprio(1);
#pragma unroll
      for (int mi = 0; mi < 4; ++mi)
#pragma unroll
        for (int ni = 0; ni < 2; ++ni)
#pragma unroll
          for (int ks = 0; ks < 2; ++ks)
            acc[mi][ni] = __builtin_amdgcn_mfma_f32_16x16x32_bf16(
                af[mi][ks], bf[ni][ks], acc[mi][ni], 0, 0, 0);
      __builtin_amdgcn_s_setprio(0);
    }
    __syncthreads();
  }
  ushort* outb = outp + (size_t)b * (PLANE * 256) + (size_t)y * 64 * 256;
#pragma unroll
  for (int mi = 0; mi < 4; ++mi)
#pragma unroll
    for (int ni = 0; ni < 2; ++ni) {
      int px = wn * 32 + ni * 16 + lm;
      int co0 = wm * 64 + mi * 16 + kg * 4;
      ushort4 h;
      h.x = f2bf(acc[mi][ni][0]); h.y = f2bf(acc[mi][ni][1]);
      h.z = f2bf(acc[mi][ni][2]); h.w = f2bf(acc[mi][ni][3]);
      *(ushort4*)(outb + (size_t)px * 256 + co0) = h;
    }
}

// ---------------------------------------------------------------------------
// fp32 NCHW feature -> bf16 NHWC
// ---------------------------------------------------------------------------
__global__ __launch_bounds__(256) void tr_nhwc(const float* __restrict__ src,
                                               ushort* __restrict__ dst) {
  __shared__ ushort T[64][264];
  int y = blockIdx.x, b = blockIdx.y, t = threadIdx.x;
  const float* s = src + (size_t)b * 1048576 + y * 64;
  int ci0 = t >> 2, f4 = t & 3;
#pragma unroll
  for (int cb = 0; cb < 4; ++cb) {
    int ci = cb * 64 + ci0;
#pragma unroll
    for (int l = 0; l < 4; ++l) {
      int px = (f4 + l * 4) * 4;
      float4 v = *(const float4*)(s + (size_t)ci * 4096 + px);
      T[px + 0][ci] = f2bf(v.x);
      T[px + 1][ci] = f2bf(v.y);
      T[px + 2][ci] = f2bf(v.z);
      T[px + 3][ci] = f2bf(v.w);
    }
  }
  __syncthreads();
  ushort* d = dst + (size_t)(b * 4096 + y * 64) * 256;
#pragma unroll
  for (int k = 0; k < 8; ++k) {
    int u = t + k * 256;
    int px = u >> 5, c32 = u & 31;
    uint4 vv = *(const uint4*)&T[px][c32 * 8];
    *(uint4*)(d + (size_t)px * 256 + c32 * 8) = vv;
  }
}

// ---------------------------------------------------------------------------
__global__ __launch_bounds__(256) void precomp_offsets(
    const float* __restrict__ off, int4* __restrict__ idx4,
    float4* __restrict__ wt4) {
  int tid = blockIdx.x * 256 + threadIdx.x;
  if (tid >= 4 * 9 * PLANE) return;
  int x = tid & 63, y = (tid >> 6) & 63;
  int kk = (tid >> 12) % 9;
  int b = tid / (9 * PLANE);
  float dy = off[((b * 18 + 2 * kk) * 64 + y) * 64 + x];
  float dx = off[((b * 18 + 2 * kk + 1) * 64 + y) * 64 + x];
  float sy = dy + (float)(y - 1 + kk / 3);
  float sx = dx + (float)(x - 1 + kk % 3);
  float y0f = floorf(sy), x0f = floorf(sx);
  float wy = sy - y0f, wx = sx - x0f;
  int y0 = (int)y0f, x0 = (int)x0f, y1 = y0 + 1, x1 = x0 + 1;
  float vy0 = ((unsigned)y0 < 64u) ? 1.f : 0.f;
  float vy1 = ((unsigned)y1 < 64u) ? 1.f : 0.f;
  float vx0 = ((unsigned)x0 < 64u) ? 1.f : 0.f;
  float vx1 = ((unsigned)x1 < 64u) ? 1.f : 0.f;
  int cy0 = min(max(y0, 0), 63), cy1 = min(max(y1, 0), 63);
  int cx0 = min(max(x0, 0), 63), cx1 = min(max(x1, 0), 63);
  idx4[tid] = make_int4(cy0 * 64 + cx0, cy0 * 64 + cx1,
                        cy1 * 64 + cx0, cy1 * 64 + cx1);
  wt4[tid] = make_float4((1.f - wy) * (1.f - wx) * vy0 * vx0,
                         (1.f - wy) * wx * vy0 * vx1,
                         wy * (1.f - wx) * vy1 * vx0, wy * wx * vy1 * vx1);
}

// ---------------------------------------------------------------------------
__global__ __launch_bounds__(256) void gn_stats(const ushort* __restrict__ x,
                                                float2* __restrict__ stats) {
  int bg = blockIdx.x;
  int b = bg >> 5, g = bg & 31;
  const uint4* base = (const uint4*)(x + (size_t)b * 1048576 + g * 8);
  float s = 0.f, q = 0.f;
#pragma unroll
  for (int k = 0; k < 16; ++k) {
    int p = threadIdx.x + k * 256;
    uint4 v = base[(size_t)p * 32];
    const ushort* h = (const ushort*)&v;
#pragma unroll
    for (int j = 0; j < 8; ++j) { float f = bf2f(h[j]); s += f; q += f * f; }
  }
#pragma unroll
  for (int o = 32; o; o >>= 1) { s += __shfl_xor(s, o); q += __shfl_xor(q, o); }
  __shared__ float ss[4], qq[4];
  int wid = threadIdx.x >> 6;
  if ((threadIdx.x & 63) == 0) { ss[wid] = s; qq[wid] = q; }
  __syncthreads();
  if (threadIdx.x == 0) {
    s = ss[0] + ss[1] + ss[2] + ss[3];
    q = qq[0] + qq[1] + qq[2] + qq[3];
    float m = s / 32768.f;
    float v = q / 32768.f - m * m;
    stats[bg] = make_float2(m, rsqrtf(v + 1e-5f));
  }
}

__global__ __launch_bounds__(256) void gn_apply(
    const ushort* __restrict__ x, const float2* __restrict__ stats,
    const float* __restrict__ gamma, const float* __restrict__ beta,
    ushort* __restrict__ out) {
  int i = blockIdx.x * 256 + threadIdx.x;
  uint4 v = ((const uint4*)x)[i];
  int cg = i & 31;
  int b = i >> 17;
  float2 st = stats[b * 32 + cg];
  const float4* gp = (const float4*)(gamma + cg * 8);
  const float4* bp = (const float4*)(beta + cg * 8);
  float4 g0 = gp[0], g1 = gp[1], b0 = bp[0], b1 = bp[1];
  float ga[8] = {g0.x, g0.y, g0.z, g0.w, g1.x, g1.y, g1.z, g1.w};
  float bb[8] = {b0.x, b0.y, b0.z, b0.w, b1.x, b1.y, b1.z, b1.w};
  ushort* h = (ushort*)&v;
#pragma unroll
  for (int j = 0; j < 8; ++j) {
    float a = st.y * ga[j];
    h[j] = f2bf(bf2f(h[j]) * a + (bb[j] - st.x * a));
  }
  ((uint4*)out)[i] = v;
}

// ---------------------------------------------------------------------------
struct WJobs {
  const float* src[12];
  ushort* dst[12];
  int cout[12];
};
__global__ __launch_bounds__(256) void wcvt(WJobs j) {
  int job = blockIdx.z, kk = blockIdx.y, co = blockIdx.x, ci = threadIdx.x;
  int Cout = j.cout[job];
  if (co >= Cout) return;
  j.dst[job][((size_t)kk * Cout + co) * 256 + ci] =
      f2bf(j.src[job][co * 2304 + ci * 9 + kk]);
}

// ---------------------------------------------------------------------------
__global__ __launch_bounds__(256) void rp_out(const float* __restrict__ off1,
                                              const float* __restrict__ off2,
                                              float* __restrict__ out) {
  int tid = blockIdx.x * 256 + threadIdx.x;
  if (tid >= OFF_ELEMS) return;
  int x = tid & 63, y = (tid >> 6) & 63;
  int ch = (tid >> 12) % 18;
  int k = ch >> 1;
  float base = (ch & 1) ? (float)(x + (k % 3) - 1) : (float)(y + (k / 3) - 1);
  float r1 = base + off1[tid];
  out[tid] = r1;
  out[OFF_ELEMS + tid] = r1 + off2[tid];
}

// ---------------------------------------------------------------------------
extern "C" void kernel_launch(void* const* d_in, const int* in_sizes, int n_in,
                              void* d_out, int out_size, void* d_ws,
                              size_t ws_size, hipStream_t stream) {
  (void)in_sizes; (void)n_in; (void)out_size; (void)ws_size;
  const float* feature = (const float*)d_in[0];
  const float* loc_ws  = (const float*)d_in[1];
  const float* loc_g   = (const float*)d_in[2];
  const float* loc_b   = (const float*)d_in[3];
  const float* cls_ws  = (const float*)d_in[4];
  const float* cls_g   = (const float*)d_in[5];
  const float* cls_b   = (const float*)d_in[6];
  const float* pi_w    = (const float*)d_in[7];
  const float* pio_w   = (const float*)d_in[8];
  const float* prd_w   = (const float*)d_in[9];
  const float* pro_w   = (const float*)d_in[10];
  const float* cd_w    = (const float*)d_in[11];
  const float* co_w    = (const float*)d_in[12];
  float* out = (float*)d_out;

  char* p = (char*)d_ws;
  int4*   idx4 = (int4*)p;            p += 147456 * 16;
  float4* wt4  = (float4*)p;          p += 147456 * 16;
  ushort* feat_bf = (ushort*)p;       p += 4194304 * 2;
  ushort* wg      = (ushort*)p;       p += 9 * 589824 * 2;
  ushort* wgpio   = (ushort*)p;       p += 41472 * 2;
  ushort* wgpro   = (ushort*)p;       p += 41472 * 2;
  ushort* wgco    = (ushort*)p;       p += 34560 * 2;
  ushort* actA    = (ushort*)p;       p += 4194304 * 2;
  ushort* actB    = (ushort*)p;       p += 4194304 * 2;
  float*  off1    = (float*)p;        p += OFF_ELEMS * 4;
  float*  off2    = (float*)p;        p += OFF_ELEMS * 4;
  float2* stats   = (float2*)p;

  ushort* WG[9];
  for (int i = 0; i < 9; ++i) WG[i] = wg + (size_t)i * 589824;

  dim3 blk(256);
  tr_nhwc<<<dim3(64, 4), blk, 0, stream>>>(feature, feat_bf);
  WJobs jobs;
  const float* srcs[12] = {loc_ws, loc_ws + 589824, loc_ws + 2 * 589824,
                           cls_ws, cls_ws + 589824, cls_ws + 2 * 589824,
                           pi_w,   prd_w,           cd_w,
                           pio_w,  pro_w,           co_w};
  ushort* dsts[12] = {WG[0], WG[1], WG[2], WG[3], WG[4], WG[5],
                      WG[6], WG[7], WG[8], wgpio, wgpro, wgco};
  int couts[12] = {256,256,256,256,256,256,256,256,256,18,18,15};
  for (int i = 0; i < 12; ++i) {
    jobs.src[i] = srcs[i]; jobs.dst[i] = dsts[i]; jobs.cout[i] = couts[i];
  }
  wcvt<<<dim3(256, 9, 12), blk, 0, stream>>>(jobs);

  auto conv = [&](const ushort* in, const ushort* w, ushort* o) {
    conv_std<256, true><<<dim3(256), dim3(512), 0, stream>>>(in, w, o, 256);
  };
  auto dconv = [&](const ushort* in, const ushort* w, ushort* o) {
    conv_dfm<<<dim3(256), dim3(512), 0, stream>>>(in, w, o, idx4, wt4);
  };
  auto sconv = [&](const ushort* in, const ushort* w, float* o, int Cout) {
    conv_std<32, false><<<dim3(256), dim3(256), 0, stream>>>(in, w, o, Cout);
  };
  auto gn = [&](const ushort* in, const float* g, const float* b, ushort* o) {
    gn_stats<<<dim3(128), blk, 0, stream>>>(in, stats);
    gn_apply<<<dim3(2048), blk, 0, stream>>>(in, stats, g, b, o);
  };

  // ---- loc branch ----
  conv(feat_bf, WG[0], actA);
  gn(actA, loc_g + 0,   loc_b + 0,   actB);
  conv(actB, WG[1], actA);
  gn(actA, loc_g + 256, loc_b + 256, actB);
  conv(actB, WG[2], actA);
  gn(actA, loc_g + 512, loc_b + 512, actB);       // actB = loc (NHWC)
  conv(actB, WG[6], actA);                        // pi
  sconv(actA, wgpio, off1, 18);                   // offset1 (fp32 NCHW)
  precomp_offsets<<<dim3(576), blk, 0, stream>>>(off1, idx4, wt4);
  dconv(actB, WG[7], actA);                       // deform(loc, offset1)
  sconv(actA, wgpro, off2, 18);                   // offset2

  // ---- cls branch ----
  conv(feat_bf, WG[3], actA);
  gn(actA, cls_g + 0,   cls_b + 0,   actB);
  conv(actB, WG[4], actA);
  gn(actA, cls_g + 256, cls_b + 256, actB);
  conv(actB, WG[5], actA);
  gn(actA, cls_g + 512, cls_b + 512, actB);       // actB = clsf
  dconv(actB, WG[8], actA);                       // deform(clsf, offset1)
  sconv(actA, wgco, out + CLS_OFF, 15);           // classification (fp32 NCHW)

  // ---- rep points ----
  rp_out<<<dim3(1152), blk, 0, stream>>>(off1, off2, out);
}